// Round 2
// baseline (20735.779 us; speedup 1.0000x reference)
//
#include <hip/hip_runtime.h>
#include <cstdint>

#define N_B 64
#define T_T 512
#define D_D 1024
#define H_H 1024
#define G4H 4096

typedef __attribute__((ext_vector_type(8))) short short8;
typedef __attribute__((ext_vector_type(4))) float f32x4;

__device__ inline uint16_t f2bf(float f) {
    union { float f; uint32_t u; } v; v.f = f;
    uint32_t u = v.u + 0x7FFFu + ((v.u >> 16) & 1u);   // RNE
    return (uint16_t)(u >> 16);
}
__device__ inline float bf2f(uint16_t h) {
    union { uint32_t u; float f; } v; v.u = ((uint32_t)h) << 16;
    return v.f;
}
__device__ inline f32x4 mfma16(short8 a, short8 b, f32x4 c) {
    return __builtin_amdgcn_mfma_f32_16x16x32_bf16(a, b, c, 0, 0, 0);
}
__device__ inline float sigm(float x) {
    return 1.0f / (1.0f + __builtin_amdgcn_exp2f(-1.44269504f * x));
}
__device__ inline float tanh_f(float x) {
    float e = __builtin_amdgcn_exp2f(2.88539008f * x);  // e^(2x)
    return 1.0f - 2.0f / (e + 1.0f);
}
__device__ inline short8 cvt_pack(float4 u0, float4 u1) {
    short8 a;
    a[0] = (short)f2bf(u0.x); a[1] = (short)f2bf(u0.y);
    a[2] = (short)f2bf(u0.z); a[3] = (short)f2bf(u0.w);
    a[4] = (short)f2bf(u1.x); a[5] = (short)f2bf(u1.y);
    a[6] = (short)f2bf(u1.z); a[7] = (short)f2bf(u1.w);
    return a;
}

// ---- W (1024 x 4096 fp32) -> WT (4096 x 1024 bf16) ----
__global__ __launch_bounds__(256) void transposeW(const float* __restrict__ W,
                                                  uint16_t* __restrict__ WT) {
    __shared__ float tile[32][33];
    const int tx = threadIdx.x & 31, ty = threadIdx.x >> 5;
    const int n0 = blockIdx.x * 32, k0 = blockIdx.y * 32;
#pragma unroll
    for (int yy = 0; yy < 32; yy += 8)
        tile[ty + yy][tx] = W[(size_t)(k0 + ty + yy) * G4H + n0 + tx];
    __syncthreads();
#pragma unroll
    for (int yy = 0; yy < 32; yy += 8)
        WT[(size_t)(n0 + ty + yy) * 1024 + k0 + tx] = f2bf(tile[tx][ty + yy]);
}

// ---- h0 fp32 -> bf16 buffer0, zero c, zero barrier ----
__global__ void prep_h0(const float* __restrict__ h0, uint16_t* __restrict__ hb,
                        float* __restrict__ c, unsigned* __restrict__ bar) {
    int i = blockIdx.x * 256 + threadIdx.x;   // 65536 total
    hb[i] = f2bf(h0[i]);
    c[i] = 0.0f;
    if (blockIdx.x == 0 && threadIdx.x < 16) bar[threadIdx.x] = 0u;
}

// ---- x fp32 -> bf16 (one-time) ----
__global__ __launch_bounds__(256) void cvt_x(const float* __restrict__ x,
                                             uint16_t* __restrict__ xb) {
    size_t i = ((size_t)blockIdx.x * 256 + threadIdx.x) * 8;
    float4 u0 = *(const float4*)(x + i);
    float4 u1 = *(const float4*)(x + i + 4);
    short8 a = cvt_pack(u0, u1);
    *(short8*)(xb + i) = a;
}

// ---- big GEMM: xW[t*64+nb][col] = xbf[nb][t][:] . Wx[:, col] (all-bf16 inputs) ----
template<bool F32OUT>
__global__ __launch_bounds__(256) void xw_gemm(const uint16_t* __restrict__ xbf,
                                               const uint16_t* __restrict__ WxT,
                                               void* __restrict__ xWout) {
    const int tid = threadIdx.x;
    const int wv = tid >> 6, lane = tid & 63;
    const int quad = lane >> 4, r = lane & 15;
    const int t = blockIdx.y;
    const int n0 = blockIdx.x * 128 + wv * 32;

    f32x4 acc[4][2] = {};
    const uint16_t* xr[4];
#pragma unroll
    for (int mt = 0; mt < 4; mt++)
        xr[mt] = xbf + ((size_t)(mt * 16 + r) * T_T + t) * D_D;
    const uint16_t* b0p = WxT + (size_t)(n0 + r) * D_D;
    const uint16_t* b1p = WxT + (size_t)(n0 + 16 + r) * D_D;

#pragma unroll 4
    for (int k0 = 0; k0 < D_D; k0 += 32) {
        const int k = k0 + quad * 8;
        short8 b0 = *(const short8*)(b0p + k);
        short8 b1 = *(const short8*)(b1p + k);
#pragma unroll
        for (int mt = 0; mt < 4; mt++) {
            short8 a = *(const short8*)(xr[mt] + k);
            acc[mt][0] = mfma16(a, b0, acc[mt][0]);
            acc[mt][1] = mfma16(a, b1, acc[mt][1]);
        }
    }
#pragma unroll
    for (int mt = 0; mt < 4; mt++)
#pragma unroll
        for (int nt = 0; nt < 2; nt++)
#pragma unroll
            for (int i = 0; i < 4; i++) {
                size_t row = (size_t)t * 64 + mt * 16 + quad * 4 + i;
                size_t idx = row * G4H + n0 + nt * 16 + r;
                if (F32OUT) ((float*)xWout)[idx] = acc[mt][nt][i];
                else        ((uint16_t*)xWout)[idx] = f2bf(acc[mt][nt][i]);
            }
}

// ---- two-level grid barrier (monotonic counters; agent-scope) ----
__device__ inline void grid_barrier(unsigned* __restrict__ bar, int step) {
    __syncthreads();
    if (threadIdx.x == 0) {
        __threadfence();   // release our block's stores to agent scope
        const int g = blockIdx.x & 7;
        unsigned old = __hip_atomic_fetch_add(&bar[g], 1u, __ATOMIC_ACQ_REL,
                                              __HIP_MEMORY_SCOPE_AGENT);
        if (old == (unsigned)(step * 32 + 31)) {            // last of 32 in group
            unsigned o2 = __hip_atomic_fetch_add(&bar[8], 1u, __ATOMIC_ACQ_REL,
                                                 __HIP_MEMORY_SCOPE_AGENT);
            if (o2 == (unsigned)(step * 8 + 7)) {           // last group
                __hip_atomic_store(&bar[9], (unsigned)(step + 1), __ATOMIC_RELEASE,
                                   __HIP_MEMORY_SCOPE_AGENT);
            }
        }
        while (__hip_atomic_load(&bar[9], __ATOMIC_ACQUIRE,
                                 __HIP_MEMORY_SCOPE_AGENT) <= (unsigned)step) {
            __builtin_amdgcn_s_sleep(2);
        }
        __threadfence();   // acquire: invalidate stale cache lines
    }
    __syncthreads();
}

// ---- persistent recurrence kernel ----
// 256 blocks x 256 thr. Block bj owns h-cols j0..j0+3 for ALL 4 gates, packed
// into ONE 16-col MFMA N-tile: tile-col p -> gate (p>>2), j = j0 + (p&3).
// 4 waves M-split (wave wv -> rows wv*16..wv*16+15). Wh slice (16 cols x 1024 K,
// 32 KB) resident in LDS for all 512 steps. c in registers. Gates combined via
// shfl_xor(4/8) within the 16-lane row-group -> no reduce LDS.
template<int MODE>   // 1 = xW bf16, 2 = xW fp32
__global__ __launch_bounds__(256) void lstm_persist(
    uint16_t* __restrict__ hb, const uint16_t* __restrict__ WhT,
    const void* __restrict__ xW, const float* __restrict__ bias,
    float* __restrict__ out, unsigned* __restrict__ bar) {
    __shared__ short8 wh[128 * 16];   // [k-chunk of 8][tile-col p] = 32 KB
    const int tid = threadIdx.x;
    const int wv = tid >> 6, lane = tid & 63;
    const int quad = lane >> 4, r = lane & 15;
    const int q = r >> 2, jj = r & 3;
    const int j0 = blockIdx.x * 4;
    const int j = j0 + jj;

    // fill Wh LDS slice (once)
    for (int idx = tid; idx < 2048; idx += 256) {
        const int chunk = idx >> 4, p = idx & 15;
        const int col = (p >> 2) * H_H + j0 + (p & 3);
        wh[idx] = *(const short8*)(WhT + (size_t)col * H_H + chunk * 8);
    }
    // per-lane bias for the 4 gates at column j
    float bsr[4];
#pragma unroll
    for (int g = 0; g < 4; g++) bsr[g] = bias[g * H_H + j];

    float creg[4] = {0.f, 0.f, 0.f, 0.f};
    __syncthreads();

    for (int t = 0; t < T_T; t++) {
        const uint16_t* hin = hb + (size_t)(t & 1) * (N_B * H_H);
        uint16_t* hnx = hb + (size_t)((t + 1) & 1) * (N_B * H_H);
        const uint16_t* arow = hin + (size_t)(wv * 16 + r) * H_H;

        f32x4 acc = {0.f, 0.f, 0.f, 0.f};
#pragma unroll 8
        for (int kk = 0; kk < 32; kk++) {
            short8 a = *(const short8*)(arow + kk * 32 + quad * 8);
            short8 b = wh[(kk * 4 + quad) * 16 + r];
            acc = mfma16(a, b, acc);
        }

        // epilogue: C[row=quad*4+i][col=r]; col r <-> (gate q, jj)
#pragma unroll
        for (int i = 0; i < 4; i++) {
            const int m = wv * 16 + quad * 4 + i;
            float v = acc[i];
            float a4 = __shfl_xor(v, 4);
            float a8 = __shfl_xor(v, 8);
            float a12 = __shfl_xor(a4, 8);
            float arr[4] = {v, a4, a8, a12};   // arr[x] = gate (q^x) at (m, jj)
            float s0 = arr[q], s1 = arr[q ^ 1], s2 = arr[q ^ 2], s3 = arr[q ^ 3];
            size_t xbase = ((size_t)t * N_B + m) * G4H + j;
            if (MODE == 2) {
                const float* xp = (const float*)xW + xbase;
                s0 += xp[0]; s1 += xp[H_H]; s2 += xp[2 * H_H]; s3 += xp[3 * H_H];
            } else {
                const uint16_t* xp = (const uint16_t*)xW + xbase;
                s0 += bf2f(xp[0]); s1 += bf2f(xp[H_H]);
                s2 += bf2f(xp[2 * H_H]); s3 += bf2f(xp[3 * H_H]);
            }
            s0 += bsr[0]; s1 += bsr[1]; s2 += bsr[2]; s3 += bsr[3];
            float i_ = sigm(s0), f_ = sigm(s1), o_ = sigm(s2), g_ = tanh_f(s3);
            float cn = f_ * creg[i] + i_ * g_;
            creg[i] = cn;                       // redundant across q-copies, consistent
            float hn = o_ * tanh_f(cn);
            if (q == 0) {
                hnx[m * H_H + j] = f2bf(hn);
                out[((size_t)m * T_T + t) * H_H + j] = hn;
            }
        }
        grid_barrier(bar, t);
    }
}

// ---- mode-0 fallback: per-step kernel, fused x@Wx (no xW workspace) ----
__global__ __launch_bounds__(256) void lstm_step0(
    const uint16_t* __restrict__ hin, uint16_t* __restrict__ hout,
    float* __restrict__ cst, const uint16_t* __restrict__ WhT,
    const uint16_t* __restrict__ WxT, const float* __restrict__ x,
    const float* __restrict__ bias, float* __restrict__ out, int t) {
    __shared__ float red[4][32 * 32];
    const int tid = threadIdx.x;
    const int wv = tid >> 6, lane = tid & 63;
    const int quad = lane >> 4, r = lane & 15;
    const int bm = blockIdx.x & 1, bj = blockIdx.x >> 1;
    const int j0 = bj * 8, m0 = bm * 32;
    const int colA = (r >> 3) * H_H + j0 + (r & 7);
    const int colB = (2 + (r >> 3)) * H_H + j0 + (r & 7);

    f32x4 acc[2][2] = {};
    if (wv < 2) {
        const int kb = wv * 512;
        const float* a0p = x + ((size_t)(m0 + r) * T_T + t) * D_D + kb;
        const float* a1p = x + ((size_t)(m0 + 16 + r) * T_T + t) * D_D + kb;
        const uint16_t* b0p = WxT + (size_t)colA * D_D + kb;
        const uint16_t* b1p = WxT + (size_t)colB * D_D + kb;
#pragma unroll 4
        for (int kk = 0; kk < 512; kk += 32) {
            const int k = kk + quad * 8;
            short8 b0 = *(const short8*)(b0p + k);
            short8 b1 = *(const short8*)(b1p + k);
            short8 a0 = cvt_pack(*(const float4*)(a0p + k), *(const float4*)(a0p + k + 4));
            short8 a1 = cvt_pack(*(const float4*)(a1p + k), *(const float4*)(a1p + k + 4));
            acc[0][0] = mfma16(a0, b0, acc[0][0]);
            acc[0][1] = mfma16(a0, b1, acc[0][1]);
            acc[1][0] = mfma16(a1, b0, acc[1][0]);
            acc[1][1] = mfma16(a1, b1, acc[1][1]);
        }
    } else {
        const int kb = (wv - 2) * 512;
        const uint16_t* a0p = hin + (size_t)(m0 + r) * H_H + kb;
        const uint16_t* a1p = hin + (size_t)(m0 + 16 + r) * H_H + kb;
        const uint16_t* b0p = WhT + (size_t)colA * H_H + kb;
        const uint16_t* b1p = WhT + (size_t)colB * H_H + kb;
#pragma unroll 4
        for (int kk = 0; kk < 512; kk += 32) {
            const int k = kk + quad * 8;
            short8 a0 = *(const short8*)(a0p + k);
            short8 a1 = *(const short8*)(a1p + k);
            short8 b0 = *(const short8*)(b0p + k);
            short8 b1 = *(const short8*)(b1p + k);
            acc[0][0] = mfma16(a0, b0, acc[0][0]);
            acc[0][1] = mfma16(a0, b1, acc[0][1]);
            acc[1][0] = mfma16(a1, b0, acc[1][0]);
            acc[1][1] = mfma16(a1, b1, acc[1][1]);
        }
    }
#pragma unroll
    for (int mt = 0; mt < 2; mt++)
#pragma unroll
        for (int nt = 0; nt < 2; nt++)
#pragma unroll
            for (int i = 0; i < 4; i++)
                red[wv][(mt * 16 + quad * 4 + i) * 32 + nt * 16 + r] = acc[mt][nt][i];
    __syncthreads();

    const int mrow = tid >> 3, jj = tid & 7;
    const int m = m0 + mrow, j = j0 + jj;
    float av[4];
#pragma unroll
    for (int g = 0; g < 4; g++) {
        int idx = mrow * 32 + g * 8 + jj;
        av[g] = red[0][idx] + red[1][idx] + red[2][idx] + red[3][idx] + bias[g * H_H + j];
    }
    float i_ = sigm(av[0]), f_ = sigm(av[1]), o_ = sigm(av[2]), g_ = tanh_f(av[3]);
    float cp = cst[m * H_H + j];
    float cn = f_ * cp + i_ * g_;
    cst[m * H_H + j] = cn;
    float hn = o_ * tanh_f(cn);
    hout[m * H_H + j] = f2bf(hn);
    out[((size_t)m * T_T + t) * H_H + j] = hn;
}

extern "C" void kernel_launch(void* const* d_in, const int* in_sizes, int n_in,
                              void* d_out, int out_size, void* d_ws, size_t ws_size,
                              hipStream_t stream) {
    const float* x    = (const float*)d_in[0];
    const float* h0   = (const float*)d_in[1];
    const float* Wx   = (const float*)d_in[2];
    const float* Wh   = (const float*)d_in[3];
    const float* bias = (const float*)d_in[4];
    float* out = (float*)d_out;

    char* wsb = (char*)d_ws;
    uint16_t* WxT = (uint16_t*)(wsb + 0);             // 8 MB
    uint16_t* WhT = (uint16_t*)(wsb + 8388608);       // 8 MB
    uint16_t* hb  = (uint16_t*)(wsb + 16777216);      // 2 x 64x1024 bf16
    float* cst    = (float*)(wsb + 17039360);         // 64x1024 fp32 (mode 0)
    unsigned* bar = (unsigned*)(wsb + 17301504);      // 16 uints
    uint16_t* xbf = (uint16_t*)(wsb + 17305600);      // 64 MB bf16 x
    void* xW      = (void*)(wsb + 84414464);
    const size_t xw_elems = (size_t)G4H * N_B * T_T;  // 134,217,728
    const size_t need2 = 84414464ull + xw_elems * 4;  // ~592 MB
    const size_t need1 = 84414464ull + xw_elems * 2;  // ~336 MB

    int mode = 0;
    if (ws_size >= need2) mode = 2;
    else if (ws_size >= need1) mode = 1;

    transposeW<<<dim3(128, 32), dim3(256), 0, stream>>>(Wx, WxT);
    transposeW<<<dim3(128, 32), dim3(256), 0, stream>>>(Wh, WhT);
    prep_h0<<<dim3(256), dim3(256), 0, stream>>>(h0, hb, cst, bar);

    if (mode >= 1) {
        cvt_x<<<dim3(16384), dim3(256), 0, stream>>>(x, xbf);
        if (mode == 2) xw_gemm<true ><<<dim3(32, 512), dim3(256), 0, stream>>>(xbf, WxT, xW);
        else           xw_gemm<false><<<dim3(32, 512), dim3(256), 0, stream>>>(xbf, WxT, xW);
        if (mode == 2)
            lstm_persist<2><<<dim3(256), dim3(256), 0, stream>>>(hb, WhT, xW, bias, out, bar);
        else
            lstm_persist<1><<<dim3(256), dim3(256), 0, stream>>>(hb, WhT, xW, bias, out, bar);
    } else {
        for (int t = 0; t < T_T; t++) {
            uint16_t* hin  = hb + (size_t)(t & 1) * (N_B * H_H);
            uint16_t* hout = hb + (size_t)((t + 1) & 1) * (N_B * H_H);
            lstm_step0<<<dim3(256), dim3(256), 0, stream>>>(hin, hout, cst, WhT, WxT, x, bias, out, t);
        }
    }
}

// Round 3
// 10064.964 us; speedup vs baseline: 2.0602x; 2.0602x over previous
//
#include <hip/hip_runtime.h>
#include <cstdint>

#define N_B 64
#define T_T 512
#define D_D 1024
#define H_H 1024
#define G4H 4096
#define NCONS 128   // consumer blocks in persistent kernel
#define JB 8        // j-columns owned per consumer block

typedef __attribute__((ext_vector_type(8))) short short8;
typedef __attribute__((ext_vector_type(4))) float f32x4;

__device__ inline uint16_t f2bf(float f) {
    union { float f; uint32_t u; } v; v.f = f;
    uint32_t u = v.u + 0x7FFFu + ((v.u >> 16) & 1u);   // RNE
    return (uint16_t)(u >> 16);
}
__device__ inline float bf2f(uint16_t h) {
    union { uint32_t u; float f; } v; v.u = ((uint32_t)h) << 16;
    return v.f;
}
__device__ inline f32x4 mfma16(short8 a, short8 b, f32x4 c) {
    return __builtin_amdgcn_mfma_f32_16x16x32_bf16(a, b, c, 0, 0, 0);
}
__device__ inline float sigm(float x) {
    return 1.0f / (1.0f + __builtin_amdgcn_exp2f(-1.44269504f * x));
}
__device__ inline float tanh_f(float x) {
    float e = __builtin_amdgcn_exp2f(2.88539008f * x);  // e^(2x)
    return 1.0f - 2.0f / (e + 1.0f);
}
__device__ inline short8 cvt_pack(float4 u0, float4 u1) {
    short8 a;
    a[0] = (short)f2bf(u0.x); a[1] = (short)f2bf(u0.y);
    a[2] = (short)f2bf(u0.z); a[3] = (short)f2bf(u0.w);
    a[4] = (short)f2bf(u1.x); a[5] = (short)f2bf(u1.y);
    a[6] = (short)f2bf(u1.z); a[7] = (short)f2bf(u1.w);
    return a;
}

// ---- W (1024 x 4096 fp32) -> WT (4096 x 1024 bf16) ----
__global__ __launch_bounds__(256) void transposeW(const float* __restrict__ W,
                                                  uint16_t* __restrict__ WT) {
    __shared__ float tile[32][33];
    const int tx = threadIdx.x & 31, ty = threadIdx.x >> 5;
    const int n0 = blockIdx.x * 32, k0 = blockIdx.y * 32;
#pragma unroll
    for (int yy = 0; yy < 32; yy += 8)
        tile[ty + yy][tx] = W[(size_t)(k0 + ty + yy) * G4H + n0 + tx];
    __syncthreads();
#pragma unroll
    for (int yy = 0; yy < 32; yy += 8)
        WT[(size_t)(n0 + ty + yy) * 1024 + k0 + tx] = f2bf(tile[tx][ty + yy]);
}

// ---- h0 fp32 -> bf16 buffer0, zero c, zero barrier ----
__global__ void prep_h0(const float* __restrict__ h0, uint16_t* __restrict__ hb,
                        float* __restrict__ c, unsigned* __restrict__ bar) {
    int i = blockIdx.x * 256 + threadIdx.x;   // 65536 total
    hb[i] = f2bf(h0[i]);
    c[i] = 0.0f;
    if (blockIdx.x == 0 && threadIdx.x < 16) bar[threadIdx.x] = 0u;
}

// ---- x fp32 -> bf16 (one-time) ----
__global__ __launch_bounds__(256) void cvt_x(const float* __restrict__ x,
                                             uint16_t* __restrict__ xb) {
    size_t i = ((size_t)blockIdx.x * 256 + threadIdx.x) * 8;
    float4 u0 = *(const float4*)(x + i);
    float4 u1 = *(const float4*)(x + i + 4);
    short8 a = cvt_pack(u0, u1);
    *(short8*)(xb + i) = a;
}

// ---- big GEMM: xW[t*64+nb][col] = xbf[nb][t][:] . Wx[:, col] (all-bf16 inputs) ----
template<bool F32OUT>
__global__ __launch_bounds__(256) void xw_gemm(const uint16_t* __restrict__ xbf,
                                               const uint16_t* __restrict__ WxT,
                                               void* __restrict__ xWout) {
    const int tid = threadIdx.x;
    const int wv = tid >> 6, lane = tid & 63;
    const int quad = lane >> 4, r = lane & 15;
    const int t = blockIdx.y;
    const int n0 = blockIdx.x * 128 + wv * 32;

    f32x4 acc[4][2] = {};
    const uint16_t* xr[4];
#pragma unroll
    for (int mt = 0; mt < 4; mt++)
        xr[mt] = xbf + ((size_t)(mt * 16 + r) * T_T + t) * D_D;
    const uint16_t* b0p = WxT + (size_t)(n0 + r) * D_D;
    const uint16_t* b1p = WxT + (size_t)(n0 + 16 + r) * D_D;

#pragma unroll 4
    for (int k0 = 0; k0 < D_D; k0 += 32) {
        const int k = k0 + quad * 8;
        short8 b0 = *(const short8*)(b0p + k);
        short8 b1 = *(const short8*)(b1p + k);
#pragma unroll
        for (int mt = 0; mt < 4; mt++) {
            short8 a = *(const short8*)(xr[mt] + k);
            acc[mt][0] = mfma16(a, b0, acc[mt][0]);
            acc[mt][1] = mfma16(a, b1, acc[mt][1]);
        }
    }
#pragma unroll
    for (int mt = 0; mt < 4; mt++)
#pragma unroll
        for (int nt = 0; nt < 2; nt++)
#pragma unroll
            for (int i = 0; i < 4; i++) {
                size_t row = (size_t)t * 64 + mt * 16 + quad * 4 + i;
                size_t idx = row * G4H + n0 + nt * 16 + r;
                if (F32OUT) ((float*)xWout)[idx] = acc[mt][nt][i];
                else        ((uint16_t*)xWout)[idx] = f2bf(acc[mt][nt][i]);
            }
}

// ---- persistent recurrence, v2 ----
// 128 blocks x 512 thr (8 waves). Block owns j-cols j0..j0+7 for all 4 gates
// (32 gate-cols = 2 MFMA N-tiles; tile nt, tile-col p: gate = nt*2+(p>>3),
// j = j0+(p&7)). Wave w: mt = w&3 (rows mt*16..+16), nt = (w>>2)&1.
// Wh slice lives in REGISTERS (breg[32], 128 VGPRs/lane) -> zero per-step LDS
// B-traffic. c-state in one register per epilogue thread. Barrier: single
// monotonic counter, RELEASE add, RELAXED polling (no per-poll L2 invalidate),
// ONE acquire fence per block per step.
template<int MODE>   // 1 = xW bf16, 2 = xW fp32
__global__ __launch_bounds__(512, 2) void lstm_persist2(
    uint16_t* __restrict__ hb, const uint16_t* __restrict__ WhT,
    const void* __restrict__ xW, const float* __restrict__ bias,
    float* __restrict__ out, unsigned* __restrict__ bar) {
    __shared__ float red[2][4][256];   // [nt][mt][row*16+col] = 8 KB
    const int tid = threadIdx.x;
    const int w = tid >> 6, lane = tid & 63;
    const int quad = lane >> 4, r = lane & 15;
    const int mt = w & 3, nt = (w >> 2) & 1;
    const int j0 = blockIdx.x * JB;

    // Wh slice -> registers (one-time). Lane holds col p=r of tile nt.
    const int g = nt * 2 + (r >> 3);
    const int col = g * H_H + j0 + (r & 7);
    const uint16_t* wcp = WhT + (size_t)col * H_H + quad * 8;
    short8 breg[32];
#pragma unroll
    for (int kk = 0; kk < 32; kk++)
        breg[kk] = *(const short8*)(wcp + kk * 32);

    // epilogue-role constants: thread -> (row em, col ej)
    const int em = tid >> 3;
    const int jj = tid & 7;
    const int ej = j0 + jj;
    float bs[4];
#pragma unroll
    for (int gg = 0; gg < 4; gg++) bs[gg] = bias[gg * H_H + ej];
    float creg = 0.0f;

    for (int t = 0; t < T_T; t++) {
        const uint16_t* hin = hb + (size_t)(t & 1) * (N_B * H_H);
        uint16_t* hnx = hb + (size_t)((t + 1) & 1) * (N_B * H_H);

        // prefetch xW values for epilogue (hide HBM latency behind K-loop)
        float xv[4];
        {
            size_t xb = ((size_t)t * N_B + em) * G4H + ej;
            if (MODE == 2) {
                const float* xp = (const float*)xW + xb;
#pragma unroll
                for (int gg = 0; gg < 4; gg++) xv[gg] = xp[gg * H_H];
            } else {
                const uint16_t* xp = (const uint16_t*)xW + xb;
#pragma unroll
                for (int gg = 0; gg < 4; gg++) xv[gg] = bf2f(xp[gg * H_H]);
            }
        }

        // h @ Wh-slice: K=1024, fully unrolled so breg[] stays in VGPRs
        const uint16_t* arow = hin + (size_t)(mt * 16 + r) * H_H + quad * 8;
        f32x4 acc = {0.f, 0.f, 0.f, 0.f};
#pragma unroll
        for (int kk = 0; kk < 32; kk++) {
            short8 a = *(const short8*)(arow + kk * 32);
            acc = mfma16(a, breg[kk], acc);
        }
#pragma unroll
        for (int i = 0; i < 4; i++)
            red[nt][mt][(quad * 4 + i) * 16 + r] = acc[i];
        __syncthreads();

        // epilogue
        float av[4];
#pragma unroll
        for (int gg = 0; gg < 4; gg++)
            av[gg] = red[gg >> 1][em >> 4][(em & 15) * 16 + (gg & 1) * 8 + jj]
                     + xv[gg] + bs[gg];
        float i_ = sigm(av[0]), f_ = sigm(av[1]), o_ = sigm(av[2]), g_ = tanh_f(av[3]);
        float cn = f_ * creg + i_ * g_;
        creg = cn;
        float hn = o_ * tanh_f(cn);
        hnx[em * H_H + ej] = f2bf(hn);
        __builtin_nontemporal_store(hn, &out[((size_t)em * T_T + t) * H_H + ej]);

        // grid barrier: release add, relaxed poll, single acquire fence
        __syncthreads();   // all waves' hnx stores drained to L2 before release
        if (tid == 0) {
            __hip_atomic_fetch_add(&bar[0], 1u, __ATOMIC_RELEASE,
                                   __HIP_MEMORY_SCOPE_AGENT);
            const unsigned tgt = (unsigned)(NCONS * (t + 1));
            while (__hip_atomic_load(&bar[0], __ATOMIC_RELAXED,
                                     __HIP_MEMORY_SCOPE_AGENT) < tgt)
                __builtin_amdgcn_s_sleep(4);
            __builtin_amdgcn_fence(__ATOMIC_ACQUIRE, "agent");
        }
        __syncthreads();
    }
}

// ---- mode-0 fallback: per-step kernel, fused x@Wx (no xW workspace) ----
__global__ __launch_bounds__(256) void lstm_step0(
    const uint16_t* __restrict__ hin, uint16_t* __restrict__ hout,
    float* __restrict__ cst, const uint16_t* __restrict__ WhT,
    const uint16_t* __restrict__ WxT, const float* __restrict__ x,
    const float* __restrict__ bias, float* __restrict__ out, int t) {
    __shared__ float red[4][32 * 32];
    const int tid = threadIdx.x;
    const int wv = tid >> 6, lane = tid & 63;
    const int quad = lane >> 4, r = lane & 15;
    const int bm = blockIdx.x & 1, bj = blockIdx.x >> 1;
    const int j0 = bj * 8, m0 = bm * 32;
    const int colA = (r >> 3) * H_H + j0 + (r & 7);
    const int colB = (2 + (r >> 3)) * H_H + j0 + (r & 7);

    f32x4 acc[2][2] = {};
    if (wv < 2) {
        const int kb = wv * 512;
        const float* a0p = x + ((size_t)(m0 + r) * T_T + t) * D_D + kb;
        const float* a1p = x + ((size_t)(m0 + 16 + r) * T_T + t) * D_D + kb;
        const uint16_t* b0p = WxT + (size_t)colA * D_D + kb;
        const uint16_t* b1p = WxT + (size_t)colB * D_D + kb;
#pragma unroll 4
        for (int kk = 0; kk < 512; kk += 32) {
            const int k = kk + quad * 8;
            short8 b0 = *(const short8*)(b0p + k);
            short8 b1 = *(const short8*)(b1p + k);
            short8 a0 = cvt_pack(*(const float4*)(a0p + k), *(const float4*)(a0p + k + 4));
            short8 a1 = cvt_pack(*(const float4*)(a1p + k), *(const float4*)(a1p + k + 4));
            acc[0][0] = mfma16(a0, b0, acc[0][0]);
            acc[0][1] = mfma16(a0, b1, acc[0][1]);
            acc[1][0] = mfma16(a1, b0, acc[1][0]);
            acc[1][1] = mfma16(a1, b1, acc[1][1]);
        }
    } else {
        const int kb = (wv - 2) * 512;
        const uint16_t* a0p = hin + (size_t)(m0 + r) * H_H + kb;
        const uint16_t* a1p = hin + (size_t)(m0 + 16 + r) * H_H + kb;
        const uint16_t* b0p = WhT + (size_t)colA * H_H + kb;
        const uint16_t* b1p = WhT + (size_t)colB * H_H + kb;
#pragma unroll 4
        for (int kk = 0; kk < 512; kk += 32) {
            const int k = kk + quad * 8;
            short8 a0 = *(const short8*)(a0p + k);
            short8 a1 = *(const short8*)(a1p + k);
            short8 b0 = *(const short8*)(b0p + k);
            short8 b1 = *(const short8*)(b1p + k);
            acc[0][0] = mfma16(a0, b0, acc[0][0]);
            acc[0][1] = mfma16(a0, b1, acc[0][1]);
            acc[1][0] = mfma16(a1, b0, acc[1][0]);
            acc[1][1] = mfma16(a1, b1, acc[1][1]);
        }
    }
#pragma unroll
    for (int mt = 0; mt < 2; mt++)
#pragma unroll
        for (int nt = 0; nt < 2; nt++)
#pragma unroll
            for (int i = 0; i < 4; i++)
                red[wv][(mt * 16 + quad * 4 + i) * 32 + nt * 16 + r] = acc[mt][nt][i];
    __syncthreads();

    const int mrow = tid >> 3, jj = tid & 7;
    const int m = m0 + mrow, j = j0 + jj;
    float av[4];
#pragma unroll
    for (int g = 0; g < 4; g++) {
        int idx = mrow * 32 + g * 8 + jj;
        av[g] = red[0][idx] + red[1][idx] + red[2][idx] + red[3][idx] + bias[g * H_H + j];
    }
    float i_ = sigm(av[0]), f_ = sigm(av[1]), o_ = sigm(av[2]), g_ = tanh_f(av[3]);
    float cp = cst[m * H_H + j];
    float cn = f_ * cp + i_ * g_;
    cst[m * H_H + j] = cn;
    float hn = o_ * tanh_f(cn);
    hout[m * H_H + j] = f2bf(hn);
    out[((size_t)m * T_T + t) * H_H + j] = hn;
}

extern "C" void kernel_launch(void* const* d_in, const int* in_sizes, int n_in,
                              void* d_out, int out_size, void* d_ws, size_t ws_size,
                              hipStream_t stream) {
    const float* x    = (const float*)d_in[0];
    const float* h0   = (const float*)d_in[1];
    const float* Wx   = (const float*)d_in[2];
    const float* Wh   = (const float*)d_in[3];
    const float* bias = (const float*)d_in[4];
    float* out = (float*)d_out;

    char* wsb = (char*)d_ws;
    uint16_t* WxT = (uint16_t*)(wsb + 0);             // 8 MB
    uint16_t* WhT = (uint16_t*)(wsb + 8388608);       // 8 MB
    uint16_t* hb  = (uint16_t*)(wsb + 16777216);      // 2 x 64x1024 bf16
    float* cst    = (float*)(wsb + 17039360);         // 64x1024 fp32 (mode 0)
    unsigned* bar = (unsigned*)(wsb + 17301504);      // 16 uints
    uint16_t* xbf = (uint16_t*)(wsb + 17305600);      // 64 MB bf16 x
    void* xW      = (void*)(wsb + 84414464);
    const size_t xw_elems = (size_t)G4H * N_B * T_T;  // 134,217,728
    const size_t need2 = 84414464ull + xw_elems * 4;  // ~592 MB
    const size_t need1 = 84414464ull + xw_elems * 2;  // ~336 MB

    int mode = 0;
    if (ws_size >= need2) mode = 2;
    else if (ws_size >= need1) mode = 1;

    transposeW<<<dim3(128, 32), dim3(256), 0, stream>>>(Wx, WxT);
    transposeW<<<dim3(128, 32), dim3(256), 0, stream>>>(Wh, WhT);
    prep_h0<<<dim3(256), dim3(256), 0, stream>>>(h0, hb, cst, bar);

    if (mode >= 1) {
        cvt_x<<<dim3(16384), dim3(256), 0, stream>>>(x, xbf);
        if (mode == 2) xw_gemm<true ><<<dim3(32, 512), dim3(256), 0, stream>>>(xbf, WxT, xW);
        else           xw_gemm<false><<<dim3(32, 512), dim3(256), 0, stream>>>(xbf, WxT, xW);
        if (mode == 2)
            lstm_persist2<2><<<dim3(NCONS), dim3(512), 0, stream>>>(hb, WhT, xW, bias, out, bar);
        else
            lstm_persist2<1><<<dim3(NCONS), dim3(512), 0, stream>>>(hb, WhT, xW, bias, out, bar);
    } else {
        for (int t = 0; t < T_T; t++) {
            uint16_t* hin  = hb + (size_t)(t & 1) * (N_B * H_H);
            uint16_t* hout = hb + (size_t)((t + 1) & 1) * (N_B * H_H);
            lstm_step0<<<dim3(256), dim3(256), 0, stream>>>(hin, hout, cst, WhT, WxT, x, bias, out, t);
        }
    }
}